// Round 3
// baseline (266.294 us; speedup 1.0000x reference)
//
#include <hip/hip_runtime.h>

// Fused LSTM (B=4096, T=256, I=128, H=64) + projection (O=10).
// Producer/consumer wave specialization: 256 WGs x 512 threads (8 waves).
// Waves 0-3 (producers): gx(t) = bias + x(t)@W_ih.T, x loaded HBM->regs
//   (2-step ping-pong prefetch), 16 MFMAs, fp32 gx -> 2-slot LDS ring.
// Waves 4-7 (consumers): acc init = ds_read gx (C-layout direct), 8 h-MFMAs,
//   gate nonlinearities (raw v_exp/v_rcp), h exchange via swizzled LDS.
// One barrier per step, matched counts across the uniform wave-role branch.

typedef __attribute__((ext_vector_type(8))) short bf16x8;
typedef __attribute__((ext_vector_type(4))) float f32x4;

#define T_STEPS 256
#define L2E 1.44269504f

#define GX_OFF 0          // 2 x 16384 fp32 gx ring
#define H_OFF  32768      // 2 x 2048 bf16 h double buffer
#define HF_OFF 36864      // 4096 fp32 final h
#define LDS_SZ 40960

__device__ __forceinline__ short f2bf(float f) {           // prologue only
    unsigned u = __float_as_uint(f);
    u += 0x7FFFu + ((u >> 16) & 1u);
    return (short)(u >> 16);
}
__device__ __forceinline__ unsigned cvt_pk(float lo, float hi) {
    unsigned r;
    asm("v_cvt_pk_bf16_f32 %0, %1, %2" : "=v"(r) : "v"(lo), "v"(hi));
    return r;
}
__device__ __forceinline__ float frcp(float x) { float r; asm("v_rcp_f32 %0, %1" : "=v"(r) : "v"(x)); return r; }
__device__ __forceinline__ float fexp2(float x) { float r; asm("v_exp_f32 %0, %1" : "=v"(r) : "v"(x)); return r; }
__device__ __forceinline__ float sigm(float x) { return frcp(1.0f + fexp2(x * -L2E)); }
__device__ __forceinline__ float tanh_f(float x) { return 1.0f - 2.0f * frcp(1.0f + fexp2(x * (2.0f * L2E))); }

__device__ __forceinline__ bf16x8 packfrag(f32x4 a, f32x4 b) {
    union { bf16x8 s; unsigned u[4]; } w;
    w.u[0] = cvt_pk(a[0], a[1]); w.u[1] = cvt_pk(a[2], a[3]);
    w.u[2] = cvt_pk(b[0], b[1]); w.u[3] = cvt_pk(b[2], b[3]);
    return w.s;
}

#define MF(A, Bf, C) (C) = __builtin_amdgcn_mfma_f32_16x16x32_bf16((A), (Bf), (C), 0, 0, 0)
#define SYNC { asm volatile("s_waitcnt lgkmcnt(0)" ::: "memory"); __builtin_amdgcn_s_barrier(); }

__global__ __launch_bounds__(512, 2) void lstm_pc_kernel(
    const float* __restrict__ x,
    const float* __restrict__ W_ih,
    const float* __restrict__ W_hh,
    const float* __restrict__ b_ih,
    const float* __restrict__ b_hh,
    const float* __restrict__ W_out,
    const float* __restrict__ b_out,
    float* __restrict__ out)
{
    __shared__ __align__(16) char smem[LDS_SZ];

    const int tid  = threadIdx.x;
    const int lane = tid & 63;
    const int q    = tid >> 6;        // wave id: 0-3 producers, 4-7 consumers
    const int l15  = lane & 15;
    const int l4   = lane >> 4;
    const int b0   = blockIdx.x * 16;

    if (q < 4) {
        // ================= PRODUCER =================
        const int p = q;              // owns gate cols {64*nt + 16*p + l15}
        bf16x8 Bih[4][4];
        f32x4  biasC[4];
#pragma unroll
        for (int nt = 0; nt < 4; ++nt) {
            const int row = nt * 64 + p * 16 + l15;
#pragma unroll
            for (int ks = 0; ks < 4; ++ks) {
                const float* wp = W_ih + row * 128 + ks * 32 + l4 * 8;
                f32x4 a = *(const f32x4*)wp;
                f32x4 b = *(const f32x4*)(wp + 4);
                bf16x8 w;
#pragma unroll
                for (int j = 0; j < 4; ++j) { w[j] = f2bf(a[j]); w[4 + j] = f2bf(b[j]); }
                Bih[nt][ks] = w;
            }
            const float bb = b_ih[row] + b_hh[row];
            biasC[nt] = (f32x4){bb, bb, bb, bb};
        }

        // gx write addresses: slot layout [p][nt][col l15][rowblk l4] f32x4,
        // 16B-group XOR swizzle spreads all 8 bank groups evenly.
        const int gxsw = ((l15 * 64 + l4 * 16) ^ ((l15 & 7) << 4));
        const int gx_wr0 = p * 4096 + 0 * 1024 + gxsw;
        const int gx_wr1 = p * 4096 + 1 * 1024 + gxsw;
        const int gx_wr2 = p * 4096 + 2 * 1024 + gxsw;
        const int gx_wr3 = p * 4096 + 3 * 1024 + gxsw;

        // lane loads A-frag source: row l15, bytes ks*128 + l4*32 (+16)
        const float* xb = x + (size_t)(b0 + l15) * (T_STEPS * 128) + l4 * 8;

        f32x4 P0[8], P1[8];           // ping-pong: P0 = even t, P1 = odd t
#pragma unroll
        for (int ks = 0; ks < 4; ++ks) {
            P0[2 * ks]     = *(const f32x4*)(xb + ks * 32);
            P0[2 * ks + 1] = *(const f32x4*)(xb + ks * 32 + 4);
            P1[2 * ks]     = *(const f32x4*)(xb + 128 + ks * 32);
            P1[2 * ks + 1] = *(const f32x4*)(xb + 128 + ks * 32 + 4);
        }

#define PWIN(tt, E, PX)                                                        \
  {                                                                            \
    char* gxs = smem + GX_OFF + (E) * 16384;                                   \
    bf16x8 F0 = packfrag(PX[0], PX[1]);                                        \
    bf16x8 F1 = packfrag(PX[2], PX[3]);                                        \
    bf16x8 F2 = packfrag(PX[4], PX[5]);                                        \
    bf16x8 F3 = packfrag(PX[6], PX[7]);                                        \
    f32x4 a0 = biasC[0], a1 = biasC[1], a2 = biasC[2], a3 = biasC[3];          \
    MF(F0, Bih[0][0], a0); MF(F0, Bih[1][0], a1);                              \
    MF(F0, Bih[2][0], a2); MF(F0, Bih[3][0], a3);                              \
    MF(F1, Bih[0][1], a0); MF(F1, Bih[1][1], a1);                              \
    MF(F1, Bih[2][1], a2); MF(F1, Bih[3][1], a3);                              \
    MF(F2, Bih[0][2], a0); MF(F2, Bih[1][2], a1);                              \
    MF(F2, Bih[2][2], a2); MF(F2, Bih[3][2], a3);                              \
    MF(F3, Bih[0][3], a0); MF(F3, Bih[1][3], a1);                              \
    MF(F3, Bih[2][3], a2); MF(F3, Bih[3][3], a3);                              \
    {                                                                          \
      int tc = (tt) + 3; tc = tc > 255 ? 255 : tc;                             \
      const float* src = xb + (size_t)tc * 128;                                \
      PX[0] = *(const f32x4*)(src);       PX[1] = *(const f32x4*)(src + 4);    \
      PX[2] = *(const f32x4*)(src + 32);  PX[3] = *(const f32x4*)(src + 36);   \
      PX[4] = *(const f32x4*)(src + 64);  PX[5] = *(const f32x4*)(src + 68);   \
      PX[6] = *(const f32x4*)(src + 96);  PX[7] = *(const f32x4*)(src + 100);  \
    }                                                                          \
    *(f32x4*)(gxs + gx_wr0) = a0;                                              \
    *(f32x4*)(gxs + gx_wr1) = a1;                                              \
    *(f32x4*)(gxs + gx_wr2) = a2;                                              \
    *(f32x4*)(gxs + gx_wr3) = a3;                                              \
  }

        PWIN(-1, 0, P0);              // gx(0) -> slot 0; reload P0 <- x(2)
        SYNC;
        for (int t = 0; t < T_STEPS; t += 2) {
            PWIN(t,     1, P1); SYNC; // gx(t+1) -> slot 1; P1 <- x(t+3)
            PWIN(t + 1, 0, P0); SYNC; // gx(t+2) -> slot 0; P0 <- x(t+4)
        }
#undef PWIN
    } else {
        // ================= CONSUMER =================
        const int qc = q - 4;         // owns hidden cols {16*qc + l15}
        bf16x8 Bhh[4][2];
#pragma unroll
        for (int nt = 0; nt < 4; ++nt) {
            const int row = nt * 64 + qc * 16 + l15;
#pragma unroll
            for (int ks = 0; ks < 2; ++ks) {
                const float* wp = W_hh + row * 64 + ks * 32 + l4 * 8;
                f32x4 a = *(const f32x4*)wp;
                f32x4 b = *(const f32x4*)(wp + 4);
                bf16x8 w;
#pragma unroll
                for (int j = 0; j < 4; ++j) { w[j] = f2bf(a[j]); w[4 + j] = f2bf(b[j]); }
                Bhh[nt][ks] = w;
            }
        }

        const int gxsw = ((l15 * 64 + l4 * 16) ^ ((l15 & 7) << 4));
        const int gx_rd0 = qc * 4096 + 0 * 1024 + gxsw;
        const int gx_rd1 = qc * 4096 + 1 * 1024 + gxsw;
        const int gx_rd2 = qc * 4096 + 2 * 1024 + gxsw;
        const int gx_rd3 = qc * 4096 + 3 * 1024 + gxsw;

        const int jcol = qc * 16 + l15;
        const int bA0 = l4 * 4 + 0, bA1 = l4 * 4 + 1, bA2 = l4 * 4 + 2, bA3 = l4 * 4 + 3;
        const int hb_wr0 = ((bA0 * 128 + jcol * 2) ^ ((bA0 & 7) << 4) ^ ((bA0 >> 3) << 5));
        const int hb_wr1 = ((bA1 * 128 + jcol * 2) ^ ((bA1 & 7) << 4) ^ ((bA1 >> 3) << 5));
        const int hb_wr2 = ((bA2 * 128 + jcol * 2) ^ ((bA2 & 7) << 4) ^ ((bA2 >> 3) << 5));
        const int hb_wr3 = ((bA3 * 128 + jcol * 2) ^ ((bA3 & 7) << 4) ^ ((bA3 >> 3) << 5));
        const int hb_rd0 = ((l15 * 128 + 0 * 64 + l4 * 16) ^ ((l15 & 7) << 4) ^ ((l15 >> 3) << 5));
        const int hb_rd1 = ((l15 * 128 + 1 * 64 + l4 * 16) ^ ((l15 & 7) << 4) ^ ((l15 >> 3) << 5));

        // zero h(-1) buffer (buf 1, read at t=0): 256 consumer threads x 8B
        ((unsigned long long*)(smem + H_OFF + 2048))[tid - 256] = 0ull;

        float c[4]  = {0.f, 0.f, 0.f, 0.f};
        float hl[4] = {0.f, 0.f, 0.f, 0.f};

        SYNC;                          // matches producer's prologue barrier

#define CWIN(tt, E)                                                            \
  {                                                                            \
    const char* gxs = smem + GX_OFF + (E) * 16384;                             \
    const char* hbR = smem + H_OFF + ((E) ^ 1) * 2048;                         \
    char*       hbW = smem + H_OFF + (E) * 2048;                               \
    f32x4 a0 = *(const f32x4*)(gxs + gx_rd0);                                  \
    f32x4 a1 = *(const f32x4*)(gxs + gx_rd1);                                  \
    f32x4 a2 = *(const f32x4*)(gxs + gx_rd2);                                  \
    f32x4 a3 = *(const f32x4*)(gxs + gx_rd3);                                  \
    bf16x8 Ah0 = *(const bf16x8*)(hbR + hb_rd0);                               \
    bf16x8 Ah1 = *(const bf16x8*)(hbR + hb_rd1);                               \
    MF(Ah0, Bhh[0][0], a0); MF(Ah0, Bhh[1][0], a1);                            \
    MF(Ah0, Bhh[2][0], a2); MF(Ah0, Bhh[3][0], a3);                            \
    MF(Ah1, Bhh[0][1], a0); MF(Ah1, Bhh[1][1], a1);                            \
    MF(Ah1, Bhh[2][1], a2); MF(Ah1, Bhh[3][1], a3);                            \
    _Pragma("unroll")                                                          \
    for (int r = 0; r < 4; ++r) {                                              \
      float iv = sigm(a0[r]);                                                  \
      float fv = sigm(a1[r]);                                                  \
      float gv = tanh_f(a2[r]);                                                \
      float ov = sigm(a3[r]);                                                  \
      float cc = fv * c[r] + iv * gv;                                          \
      c[r] = cc;                                                               \
      hl[r] = ov * tanh_f(cc);                                                 \
    }                                                                          \
    {                                                                          \
      unsigned w01 = cvt_pk(hl[0], hl[1]);                                     \
      unsigned w23 = cvt_pk(hl[2], hl[3]);                                     \
      *(short*)(hbW + hb_wr0) = (short)w01;                                    \
      *(short*)(hbW + hb_wr1) = (short)(w01 >> 16);                            \
      *(short*)(hbW + hb_wr2) = (short)w23;                                    \
      *(short*)(hbW + hb_wr3) = (short)(w23 >> 16);                            \
    }                                                                          \
  }

        for (int t = 0; t < T_STEPS; t += 2) {
            CWIN(t,     0); SYNC;      // reads gx(t)   from slot 0
            CWIN(t + 1, 1); SYNC;      // reads gx(t+1) from slot 1
        }
#undef CWIN

        // publish final h (fp32) for the projection
#pragma unroll
        for (int r = 0; r < 4; ++r) {
            const int b = l4 * 4 + r;
            *(float*)(smem + HF_OFF + (b * 64 + jcol) * 4) = hl[r];
        }
    }

    SYNC;                              // barrier #258 for both roles

    // ---------------- projection: out = h_last @ W_out.T + b_out ----------
    if (tid < 160) {
        const int b = tid / 10;
        const int o = tid - b * 10;
        const f32x4* hf = (const f32x4*)(smem + HF_OFF + b * 256);
        const f32x4* wr = (const f32x4*)(W_out + o * 64);
        float s = b_out[o];
#pragma unroll
        for (int j4 = 0; j4 < 16; ++j4) {
            f32x4 h4 = hf[j4];
            f32x4 w4 = wr[j4];
            s += h4[0] * w4[0] + h4[1] * w4[1] + h4[2] * w4[2] + h4[3] * w4[3];
        }
        out[(b0 + b) * 10 + o] = s;
    }
}

extern "C" void kernel_launch(void* const* d_in, const int* in_sizes, int n_in,
                              void* d_out, int out_size, void* d_ws, size_t ws_size,
                              hipStream_t stream) {
    const float* x     = (const float*)d_in[0];
    const float* W_ih  = (const float*)d_in[1];
    const float* W_hh  = (const float*)d_in[2];
    const float* b_ih  = (const float*)d_in[3];
    const float* b_hh  = (const float*)d_in[4];
    const float* W_out = (const float*)d_in[5];
    const float* b_out = (const float*)d_in[6];
    (void)in_sizes; (void)n_in; (void)out_size; (void)d_ws; (void)ws_size;

    lstm_pc_kernel<<<dim3(256), dim3(512), 0, stream>>>(
        x, W_ih, W_hh, b_ih, b_hh, W_out, b_out, (float*)d_out);
}

// Round 4
// 216.568 us; speedup vs baseline: 1.2296x; 1.2296x over previous
//
#include <hip/hip_runtime.h>

// Fused LSTM (B=4096, T=256, I=128, H=64) + projection (O=10).
// 256 WGs x 512 threads (8 waves, 2/SIMD). Wave pair m = w>>1 owns the
// interleaved gate slice {64*nt + 16*m + col} (i/f/g/o for one (b,j) in one
// lane). Both waves of a pair run IDENTICAL MFMA work (2x redundant, cheap);
// half e = w&1 applies the nonlinearity + h-write only for acc rows {2e,2e+1}
// -> per-SIMD VALU/trans unchanged, but 2 waves/SIMD hide each other's
// latency (R2 was 1 wave/SIMD, ~1000 cyc/step exposed stall).
// x staged via 4-deep LDS ring (bf16 A-frags); weights in VGPRs; one
// lgkmcnt(0)+s_barrier per step; vmcnt never drained (4-window prefetch).

typedef __attribute__((ext_vector_type(8))) short bf16x8;
typedef __attribute__((ext_vector_type(4))) float f32x4;
typedef __attribute__((ext_vector_type(2))) unsigned u32x2;

#define T_STEPS 256
#define L2E 1.44269504f

#define XF_OFF 0          // 4 x 4096B bf16 x-frag ring
#define H_OFF  16384      // 2 x 2048B bf16 h double buffer
#define HF_OFF 20480      // 4096B fp32 final h
#define LDS_SZ 24576

__device__ __forceinline__ short f2bf(float f) {           // prologue only
    unsigned u = __float_as_uint(f);
    u += 0x7FFFu + ((u >> 16) & 1u);
    return (short)(u >> 16);
}
__device__ __forceinline__ unsigned cvt_pk(float lo, float hi) {
    unsigned r;
    asm("v_cvt_pk_bf16_f32 %0, %1, %2" : "=v"(r) : "v"(lo), "v"(hi));
    return r;
}
__device__ __forceinline__ float frcp(float x) { float r; asm("v_rcp_f32 %0, %1" : "=v"(r) : "v"(x)); return r; }
__device__ __forceinline__ float fexp2(float x) { float r; asm("v_exp_f32 %0, %1" : "=v"(r) : "v"(x)); return r; }
__device__ __forceinline__ float sigm(float x) { return frcp(1.0f + fexp2(x * -L2E)); }
__device__ __forceinline__ float tanh_f(float x) { return 1.0f - 2.0f * frcp(1.0f + fexp2(x * (2.0f * L2E))); }

#define MF(A, Bf, C) (C) = __builtin_amdgcn_mfma_f32_16x16x32_bf16((A), (Bf), (C), 0, 0, 0)
#define SYNC { asm volatile("s_waitcnt lgkmcnt(0)" ::: "memory"); __builtin_amdgcn_s_barrier(); }

__global__ __launch_bounds__(512, 2) void lstm_kernel(
    const float* __restrict__ x,
    const float* __restrict__ W_ih,
    const float* __restrict__ W_hh,
    const float* __restrict__ b_ih,
    const float* __restrict__ b_hh,
    const float* __restrict__ W_out,
    const float* __restrict__ b_out,
    float* __restrict__ out)
{
    __shared__ __align__(16) char smem[LDS_SZ];

    const int tid  = threadIdx.x;
    const int lane = tid & 63;
    const int w    = tid >> 6;        // wave 0..7
    const int m    = w >> 1;          // gate-slice pair 0..3
    const int e    = w & 1;           // nonlin row-half
    const int l15  = lane & 15;
    const int l4   = lane >> 4;
    const int b0   = blockIdx.x * 16;

    // ---------------- weight fragments (redundant across the pair) --------
    bf16x8 Bih[4][4];
    bf16x8 Bhh[4][2];
    f32x4  biasC[4];
#pragma unroll
    for (int nt = 0; nt < 4; ++nt) {
        const int row = nt * 64 + m * 16 + l15;
#pragma unroll
        for (int ks = 0; ks < 4; ++ks) {
            const float* p = W_ih + row * 128 + ks * 32 + l4 * 8;
            f32x4 a = *(const f32x4*)p;
            f32x4 b = *(const f32x4*)(p + 4);
            bf16x8 wv;
#pragma unroll
            for (int j = 0; j < 4; ++j) { wv[j] = f2bf(a[j]); wv[4 + j] = f2bf(b[j]); }
            Bih[nt][ks] = wv;
        }
#pragma unroll
        for (int ks = 0; ks < 2; ++ks) {
            const float* p = W_hh + row * 64 + ks * 32 + l4 * 8;
            f32x4 a = *(const f32x4*)p;
            f32x4 b = *(const f32x4*)(p + 4);
            bf16x8 wv;
#pragma unroll
            for (int j = 0; j < 4; ++j) { wv[j] = f2bf(a[j]); wv[4 + j] = f2bf(b[j]); }
            Bhh[nt][ks] = wv;
        }
        const float bb = b_ih[row] + b_hh[row];
        biasC[nt] = (f32x4){bb, bb, bb, bb};
    }

    // ---------------- address maps ----------------
    int xf_rd[4];
#pragma unroll
    for (int ks = 0; ks < 4; ++ks)
        xf_rd[ks] = (((ks * 64 + lane) * 16) ^ ((ks & 3) << 6));

    const int jcol = m * 16 + l15;
    int hb_wr[2];
#pragma unroll
    for (int u = 0; u < 2; ++u) {
        const int b = l4 * 4 + 2 * e + u;
        hb_wr[u] = ((b * 128 + jcol * 2) ^ ((b & 7) << 4) ^ ((b >> 3) << 5));
    }
    int hb_rd[2];
#pragma unroll
    for (int ks = 0; ks < 2; ++ks)
        hb_rd[ks] = ((l15 * 128 + ks * 64 + l4 * 16) ^ ((l15 & 7) << 4) ^ ((l15 >> 3) << 5));

    // x staging: thread -> one f32x4 (16B) per step; 32 threads cover a 512B
    // row contiguously. Written as 8B bf16 at the exact frag slot.
    const int srow = tid >> 5;
    const int scc  = tid & 31;
    const int sks  = scc >> 3;
    const int sl4  = (scc & 7) >> 1;
    const int sh   = scc & 1;
    const int xf_wr = (((sks * 64 + sl4 * 16 + srow) * 16 + sh * 8) ^ ((sks & 3) << 6));
    const float* xsrc = x + (size_t)(b0 + srow) * (T_STEPS * 128) + scc * 4;

    // ---------------- prologue ----------------
#pragma unroll
    for (int s = 0; s < 3; ++s) {
        f32x4 v = *(const f32x4*)(xsrc + (size_t)s * 128);
        u32x2 wv; wv.x = cvt_pk(v[0], v[1]); wv.y = cvt_pk(v[2], v[3]);
        *(u32x2*)(smem + XF_OFF + s * 4096 + xf_wr) = wv;
    }
    f32x4 P[4];
#pragma unroll
    for (int s = 0; s < 4; ++s)
        P[s] = *(const f32x4*)(xsrc + (size_t)(s + 3) * 128);

    ((unsigned*)(smem + H_OFF + 2048))[tid] = 0u;   // h(-1) = 0 (buf 1)

    SYNC;

    float c[2]  = {0.f, 0.f};
    float hl[2] = {0.f, 0.f};

    f32x4 accA[4], accB[4];
    {   // accA = bias + gx(0), from ring slot 0
        bf16x8 Ax0 = *(const bf16x8*)(smem + XF_OFF + xf_rd[0]);
        bf16x8 Ax1 = *(const bf16x8*)(smem + XF_OFF + xf_rd[1]);
        bf16x8 Ax2 = *(const bf16x8*)(smem + XF_OFF + xf_rd[2]);
        bf16x8 Ax3 = *(const bf16x8*)(smem + XF_OFF + xf_rd[3]);
#pragma unroll
        for (int nt = 0; nt < 4; ++nt) accA[nt] = biasC[nt];
        MF(Ax0, Bih[0][0], accA[0]); MF(Ax0, Bih[1][0], accA[1]);
        MF(Ax0, Bih[2][0], accA[2]); MF(Ax0, Bih[3][0], accA[3]);
        MF(Ax1, Bih[0][1], accA[0]); MF(Ax1, Bih[1][1], accA[1]);
        MF(Ax1, Bih[2][1], accA[2]); MF(Ax1, Bih[3][1], accA[3]);
        MF(Ax2, Bih[0][2], accA[0]); MF(Ax2, Bih[1][2], accA[1]);
        MF(Ax2, Bih[2][2], accA[2]); MF(Ax2, Bih[3][2], accA[3]);
        MF(Ax3, Bih[0][3], accA[0]); MF(Ax3, Bih[1][3], accA[1]);
        MF(Ax3, Bih[2][3], accA[2]); MF(Ax3, Bih[3][3], accA[3]);
    }

#define NONLIN(ACUR, R0, R1, hbW)                                              \
    {                                                                          \
      float iv0 = sigm(ACUR[0][R0]);                                           \
      float fv0 = sigm(ACUR[1][R0]);                                           \
      float gv0 = tanh_f(ACUR[2][R0]);                                         \
      float ov0 = sigm(ACUR[3][R0]);                                           \
      float iv1 = sigm(ACUR[0][R1]);                                           \
      float fv1 = sigm(ACUR[1][R1]);                                           \
      float gv1 = tanh_f(ACUR[2][R1]);                                         \
      float ov1 = sigm(ACUR[3][R1]);                                           \
      float cc0 = fv0 * c[0] + iv0 * gv0;                                      \
      float cc1 = fv1 * c[1] + iv1 * gv1;                                      \
      c[0] = cc0; c[1] = cc1;                                                  \
      hl[0] = ov0 * tanh_f(cc0);                                               \
      hl[1] = ov1 * tanh_f(cc1);                                               \
      unsigned wp = cvt_pk(hl[0], hl[1]);                                      \
      *(short*)((hbW) + hb_wr[0]) = (short)wp;                                 \
      *(short*)((hbW) + hb_wr[1]) = (short)(wp >> 16);                         \
    }

    // Window tt: h-MFMAs finish gates(tt) in ACUR; ANXT = bias + gx(tt+1);
    // stage x(tt+3); load x(tt+7); nonlin(tt) for this wave's row-half.
#define WINDOW(tt, T4, ACUR, ANXT)                                             \
  {                                                                            \
    const char* hbR = smem + H_OFF + ((((T4) & 1) ^ 1) * 2048);                \
    char*       hbW = smem + H_OFF + (((T4) & 1) * 2048);                      \
    const char* xfb = smem + XF_OFF + ((((T4) + 1) & 3) * 4096);               \
    char*       xfw = smem + XF_OFF + ((((T4) + 3) & 3) * 4096);               \
    bf16x8 Ah0 = *(const bf16x8*)(hbR + hb_rd[0]);                             \
    bf16x8 Ah1 = *(const bf16x8*)(hbR + hb_rd[1]);                             \
    MF(Ah0, Bhh[0][0], ACUR[0]); MF(Ah0, Bhh[1][0], ACUR[1]);                  \
    MF(Ah0, Bhh[2][0], ACUR[2]); MF(Ah0, Bhh[3][0], ACUR[3]);                  \
    MF(Ah1, Bhh[0][1], ACUR[0]); MF(Ah1, Bhh[1][1], ACUR[1]);                  \
    MF(Ah1, Bhh[2][1], ACUR[2]); MF(Ah1, Bhh[3][1], ACUR[3]);                  \
    bf16x8 Ax0 = *(const bf16x8*)(xfb + xf_rd[0]);                             \
    bf16x8 Ax1 = *(const bf16x8*)(xfb + xf_rd[1]);                             \
    bf16x8 Ax2 = *(const bf16x8*)(xfb + xf_rd[2]);                             \
    bf16x8 Ax3 = *(const bf16x8*)(xfb + xf_rd[3]);                             \
    ANXT[0] = biasC[0]; ANXT[1] = biasC[1];                                    \
    ANXT[2] = biasC[2]; ANXT[3] = biasC[3];                                    \
    MF(Ax0, Bih[0][0], ANXT[0]); MF(Ax0, Bih[1][0], ANXT[1]);                  \
    MF(Ax0, Bih[2][0], ANXT[2]); MF(Ax0, Bih[3][0], ANXT[3]);                  \
    MF(Ax1, Bih[0][1], ANXT[0]); MF(Ax1, Bih[1][1], ANXT[1]);                  \
    MF(Ax1, Bih[2][1], ANXT[2]); MF(Ax1, Bih[3][1], ANXT[3]);                  \
    MF(Ax2, Bih[0][2], ANXT[0]); MF(Ax2, Bih[1][2], ANXT[1]);                  \
    MF(Ax2, Bih[2][2], ANXT[2]); MF(Ax2, Bih[3][2], ANXT[3]);                  \
    MF(Ax3, Bih[0][3], ANXT[0]); MF(Ax3, Bih[1][3], ANXT[1]);                  \
    MF(Ax3, Bih[2][3], ANXT[2]); MF(Ax3, Bih[3][3], ANXT[3]);                  \
    {                                                                          \
      u32x2 wv; wv.x = cvt_pk(P[(T4)][0], P[(T4)][1]);                         \
      wv.y = cvt_pk(P[(T4)][2], P[(T4)][3]);                                   \
      *(u32x2*)(xfw + xf_wr) = wv;                                             \
      int tc = (tt) + 7; tc = tc > 255 ? 255 : tc;                             \
      P[(T4)] = *(const f32x4*)(xsrc + (size_t)tc * 128);                      \
    }                                                                          \
    if (e == 0) { NONLIN(ACUR, 0, 1, hbW) } else { NONLIN(ACUR, 2, 3, hbW) }   \
    SYNC;                                                                      \
  }

    for (int t = 0; t < T_STEPS; t += 4) {
        WINDOW(t,     0, accA, accB);
        WINDOW(t + 1, 1, accB, accA);
        WINDOW(t + 2, 2, accA, accB);
        WINDOW(t + 3, 3, accB, accA);
    }
#undef WINDOW
#undef NONLIN

    // ---------------- epilogue: out = h_last @ W_out.T + b_out -------------
#pragma unroll
    for (int u = 0; u < 2; ++u) {
        const int b = l4 * 4 + 2 * e + u;
        *(float*)(smem + HF_OFF + (b * 64 + jcol) * 4) = hl[u];
    }
    SYNC;

    if (tid < 160) {
        const int b = tid / 10;
        const int o = tid - b * 10;
        const f32x4* hf = (const f32x4*)(smem + HF_OFF + b * 256);
        const f32x4* wr = (const f32x4*)(W_out + o * 64);
        float s = b_out[o];
#pragma unroll
        for (int j4 = 0; j4 < 16; ++j4) {
            f32x4 h4 = hf[j4];
            f32x4 w4 = wr[j4];
            s += h4[0] * w4[0] + h4[1] * w4[1] + h4[2] * w4[2] + h4[3] * w4[3];
        }
        out[(b0 + b) * 10 + o] = s;
    }
}

extern "C" void kernel_launch(void* const* d_in, const int* in_sizes, int n_in,
                              void* d_out, int out_size, void* d_ws, size_t ws_size,
                              hipStream_t stream) {
    const float* x     = (const float*)d_in[0];
    const float* W_ih  = (const float*)d_in[1];
    const float* W_hh  = (const float*)d_in[2];
    const float* b_ih  = (const float*)d_in[3];
    const float* b_hh  = (const float*)d_in[4];
    const float* W_out = (const float*)d_in[5];
    const float* b_out = (const float*)d_in[6];
    (void)in_sizes; (void)n_in; (void)out_size; (void)d_ws; (void)ws_size;

    lstm_kernel<<<dim3(256), dim3(512), 0, stream>>>(
        x, W_ih, W_hh, b_ih, b_hh, W_out, b_out, (float*)d_out);
}

// Round 5
// 166.331 us; speedup vs baseline: 1.6010x; 1.3020x over previous
//
#include <hip/hip_runtime.h>

// Fused LSTM (B=4096, T=256, I=128, H=64) + projection (O=10).
// R2 base: 256 WGs x 256 threads (4 waves, 1/SIMD); wave q owns interleaved
// gate slice {64*nt + 16*q + col} so i/f/g/o for one (b,j) share a lane.
// This round: VALU-issue surgery (kernel is trans-issue-bound, ~40 wave64
// trans/step/SIMD at ~16cyc each):
//  - log2e folded into weights/bias (i,f,o rows * -L2E; g rows * +2*L2E)
//  - shared-rcp gate algebra: 7 trans per (b,j) instead of 10
//  - x-MFMAs reordered before recurrent h-MFMAs (cover ds_read h latency),
//    bias folded into first MFMA's C operand.

typedef __attribute__((ext_vector_type(8))) short bf16x8;
typedef __attribute__((ext_vector_type(4))) float f32x4;
typedef __attribute__((ext_vector_type(2))) unsigned u32x2;

#define T_STEPS 256
#define L2E 1.44269504f

#define XF_OFF 0          // 4 x 4096B bf16 x-frag ring
#define H_OFF  16384      // 2 x 2048B bf16 h double buffer
#define HF_OFF 20480      // 4096B fp32 final h
#define LDS_SZ 24576

__device__ __forceinline__ short f2bf(float f) {           // prologue only
    unsigned u = __float_as_uint(f);
    u += 0x7FFFu + ((u >> 16) & 1u);
    return (short)(u >> 16);
}
__device__ __forceinline__ unsigned cvt_pk(float lo, float hi) {
    unsigned r;
    asm("v_cvt_pk_bf16_f32 %0, %1, %2" : "=v"(r) : "v"(lo), "v"(hi));
    return r;
}
__device__ __forceinline__ float frcp(float x) { float r; asm("v_rcp_f32 %0, %1" : "=v"(r) : "v"(x)); return r; }
__device__ __forceinline__ float fexp2(float x) { float r; asm("v_exp_f32 %0, %1" : "=v"(r) : "v"(x)); return r; }

#define MF(A, Bf, C) (C) = __builtin_amdgcn_mfma_f32_16x16x32_bf16((A), (Bf), (C), 0, 0, 0)
#define SYNC { asm volatile("s_waitcnt lgkmcnt(0)" ::: "memory"); __builtin_amdgcn_s_barrier(); }

__global__ __launch_bounds__(256, 1) void lstm_kernel(
    const float* __restrict__ x,
    const float* __restrict__ W_ih,
    const float* __restrict__ W_hh,
    const float* __restrict__ b_ih,
    const float* __restrict__ b_hh,
    const float* __restrict__ W_out,
    const float* __restrict__ b_out,
    float* __restrict__ out)
{
    __shared__ __align__(16) char smem[LDS_SZ];

    const int tid  = threadIdx.x;
    const int lane = tid & 63;
    const int q    = tid >> 6;
    const int l15  = lane & 15;
    const int l4   = lane >> 4;
    const int b0   = blockIdx.x * 16;

    // ---------------- weight fragments (exp2-prescaled) ----------------
    // nt 0(i),1(f),3(o): scale -L2E  (sigmoid via exp2(-L2E*a))
    // nt 2(g):           scale +2*L2E (tanh via exp2(2*L2E*a))
    bf16x8 Bih[4][4];
    bf16x8 Bhh[4][2];
    f32x4  biasC[4];
#pragma unroll
    for (int nt = 0; nt < 4; ++nt) {
        const float scl = (nt == 2) ? (2.0f * L2E) : (-L2E);
        const int row = nt * 64 + q * 16 + l15;
#pragma unroll
        for (int ks = 0; ks < 4; ++ks) {
            const float* p = W_ih + row * 128 + ks * 32 + l4 * 8;
            f32x4 a = *(const f32x4*)p;
            f32x4 b = *(const f32x4*)(p + 4);
            bf16x8 wv;
#pragma unroll
            for (int j = 0; j < 4; ++j) { wv[j] = f2bf(a[j] * scl); wv[4 + j] = f2bf(b[j] * scl); }
            Bih[nt][ks] = wv;
        }
#pragma unroll
        for (int ks = 0; ks < 2; ++ks) {
            const float* p = W_hh + row * 64 + ks * 32 + l4 * 8;
            f32x4 a = *(const f32x4*)p;
            f32x4 b = *(const f32x4*)(p + 4);
            bf16x8 wv;
#pragma unroll
            for (int j = 0; j < 4; ++j) { wv[j] = f2bf(a[j] * scl); wv[4 + j] = f2bf(b[j] * scl); }
            Bhh[nt][ks] = wv;
        }
        const float bb = (b_ih[row] + b_hh[row]) * scl;
        biasC[nt] = (f32x4){bb, bb, bb, bb};
    }

    // ---------------- address maps ----------------
    int xf_rd[4];
#pragma unroll
    for (int ks = 0; ks < 4; ++ks)
        xf_rd[ks] = (((ks * 64 + lane) * 16) ^ ((ks & 3) << 6));

    const int jcol = q * 16 + l15;
    int hb_wr[4];
#pragma unroll
    for (int r = 0; r < 4; ++r) {
        const int b = l4 * 4 + r;
        hb_wr[r] = ((b * 128 + jcol * 2) ^ ((b & 7) << 4) ^ ((b >> 3) << 5));
    }
    int hb_rd[2];
#pragma unroll
    for (int ks = 0; ks < 2; ++ks)
        hb_rd[ks] = ((l15 * 128 + ks * 64 + l4 * 16) ^ ((l15 & 7) << 4) ^ ((l15 >> 3) << 5));

    // x staging: thread loads one f32x4 per step (32 threads cover a 512B
    // row contiguously), writes 8B bf16 at the exact frag slot.
    const int srow = tid >> 5;          // only rows 0-7 per 256 threads? no:
    const int scc  = tid & 31;          // tid>>5 in 0..7 -> 8 rows... need 16
    // 256 threads / 32 per row = 8 rows per pass; do 2 passes via srow+8.
    const int sks  = scc >> 3;
    const int sl4  = (scc & 7) >> 1;
    const int sh   = scc & 1;
    const int xf_wr0 = (((sks * 64 + sl4 * 16 + srow) * 16 + sh * 8) ^ ((sks & 3) << 6));
    const int xf_wr1 = (((sks * 64 + sl4 * 16 + srow + 8) * 16 + sh * 8) ^ ((sks & 3) << 6));
    const float* xsrc0 = x + (size_t)(b0 + srow) * (T_STEPS * 128) + scc * 4;
    const float* xsrc1 = x + (size_t)(b0 + srow + 8) * (T_STEPS * 128) + scc * 4;

    // ---------------- prologue ----------------
#pragma unroll
    for (int s = 0; s < 3; ++s) {
        f32x4 v0 = *(const f32x4*)(xsrc0 + (size_t)s * 128);
        f32x4 v1 = *(const f32x4*)(xsrc1 + (size_t)s * 128);
        u32x2 wv0; wv0.x = cvt_pk(v0[0], v0[1]); wv0.y = cvt_pk(v0[2], v0[3]);
        u32x2 wv1; wv1.x = cvt_pk(v1[0], v1[1]); wv1.y = cvt_pk(v1[2], v1[3]);
        *(u32x2*)(smem + XF_OFF + s * 4096 + xf_wr0) = wv0;
        *(u32x2*)(smem + XF_OFF + s * 4096 + xf_wr1) = wv1;
    }
    f32x4 P0[4], P1[4];
#pragma unroll
    for (int s = 0; s < 4; ++s) {
        P0[s] = *(const f32x4*)(xsrc0 + (size_t)(s + 3) * 128);
        P1[s] = *(const f32x4*)(xsrc1 + (size_t)(s + 3) * 128);
    }
    ((unsigned long long*)(smem + H_OFF + 2048))[tid] = 0ull;  // h(-1)=0 (buf 1)

    SYNC;

    float c[4]  = {0.f, 0.f, 0.f, 0.f};
    float hl[4] = {0.f, 0.f, 0.f, 0.f};

    f32x4 accA[4], accB[4];
    {   // accA = bias + gx(0), ring slot 0
        bf16x8 Ax0 = *(const bf16x8*)(smem + XF_OFF + xf_rd[0]);
        bf16x8 Ax1 = *(const bf16x8*)(smem + XF_OFF + xf_rd[1]);
        bf16x8 Ax2 = *(const bf16x8*)(smem + XF_OFF + xf_rd[2]);
        bf16x8 Ax3 = *(const bf16x8*)(smem + XF_OFF + xf_rd[3]);
        accA[0] = biasC[0]; accA[1] = biasC[1]; accA[2] = biasC[2]; accA[3] = biasC[3];
        MF(Ax0, Bih[0][0], accA[0]); MF(Ax0, Bih[1][0], accA[1]);
        MF(Ax0, Bih[2][0], accA[2]); MF(Ax0, Bih[3][0], accA[3]);
        MF(Ax1, Bih[0][1], accA[0]); MF(Ax1, Bih[1][1], accA[1]);
        MF(Ax1, Bih[2][1], accA[2]); MF(Ax1, Bih[3][1], accA[3]);
        MF(Ax2, Bih[0][2], accA[0]); MF(Ax2, Bih[1][2], accA[1]);
        MF(Ax2, Bih[2][2], accA[2]); MF(Ax2, Bih[3][2], accA[3]);
        MF(Ax3, Bih[0][3], accA[0]); MF(Ax3, Bih[1][3], accA[1]);
        MF(Ax3, Bih[2][3], accA[2]); MF(Ax3, Bih[3][3], accA[3]);
    }

    // Window tt: x-MFMAs build ANXT = bias + gx(tt+1) (covers h ds_read
    // latency); h-MFMAs complete gates(tt) in ACUR; stage x(tt+3); load
    // x(tt+7); shared-rcp nonlin(tt); write h(tt).
#define WINDOW(tt, T4, ACUR, ANXT)                                             \
  {                                                                            \
    const char* hbR = smem + H_OFF + ((((T4) & 1) ^ 1) * 2048);                \
    char*       hbW = smem + H_OFF + (((T4) & 1) * 2048);                      \
    const char* xfb = smem + XF_OFF + ((((T4) + 1) & 3) * 4096);               \
    char*       xfw = smem + XF_OFF + ((((T4) + 3) & 3) * 4096);               \
    bf16x8 Ax0 = *(const bf16x8*)(xfb + xf_rd[0]);                             \
    bf16x8 Ax1 = *(const bf16x8*)(xfb + xf_rd[1]);                             \
    bf16x8 Ax2 = *(const bf16x8*)(xfb + xf_rd[2]);                             \
    bf16x8 Ax3 = *(const bf16x8*)(xfb + xf_rd[3]);                             \
    bf16x8 Ah0 = *(const bf16x8*)(hbR + hb_rd[0]);                             \
    bf16x8 Ah1 = *(const bf16x8*)(hbR + hb_rd[1]);                             \
    ANXT[0] = biasC[0]; ANXT[1] = biasC[1];                                    \
    ANXT[2] = biasC[2]; ANXT[3] = biasC[3];                                    \
    MF(Ax0, Bih[0][0], ANXT[0]); MF(Ax0, Bih[1][0], ANXT[1]);                  \
    MF(Ax0, Bih[2][0], ANXT[2]); MF(Ax0, Bih[3][0], ANXT[3]);                  \
    MF(Ax1, Bih[0][1], ANXT[0]); MF(Ax1, Bih[1][1], ANXT[1]);                  \
    MF(Ax1, Bih[2][1], ANXT[2]); MF(Ax1, Bih[3][1], ANXT[3]);                  \
    MF(Ax2, Bih[0][2], ANXT[0]); MF(Ax2, Bih[1][2], ANXT[1]);                  \
    MF(Ax2, Bih[2][2], ANXT[2]); MF(Ax2, Bih[3][2], ANXT[3]);                  \
    MF(Ax3, Bih[0][3], ANXT[0]); MF(Ax3, Bih[1][3], ANXT[1]);                  \
    MF(Ax3, Bih[2][3], ANXT[2]); MF(Ax3, Bih[3][3], ANXT[3]);                  \
    MF(Ah0, Bhh[0][0], ACUR[0]); MF(Ah0, Bhh[1][0], ACUR[1]);                  \
    MF(Ah0, Bhh[2][0], ACUR[2]); MF(Ah0, Bhh[3][0], ACUR[3]);                  \
    MF(Ah1, Bhh[0][1], ACUR[0]); MF(Ah1, Bhh[1][1], ACUR[1]);                  \
    MF(Ah1, Bhh[2][1], ACUR[2]); MF(Ah1, Bhh[3][1], ACUR[3]);                  \
    {                                                                          \
      u32x2 wv0; wv0.x = cvt_pk(P0[(T4)][0], P0[(T4)][1]);                     \
      wv0.y = cvt_pk(P0[(T4)][2], P0[(T4)][3]);                                \
      u32x2 wv1; wv1.x = cvt_pk(P1[(T4)][0], P1[(T4)][1]);                     \
      wv1.y = cvt_pk(P1[(T4)][2], P1[(T4)][3]);                                \
      *(u32x2*)(xfw + xf_wr0) = wv0;                                           \
      *(u32x2*)(xfw + xf_wr1) = wv1;                                           \
      const int tc = ((tt) + 7) & 255;                                         \
      P0[(T4)] = *(const f32x4*)(xsrc0 + (size_t)tc * 128);                    \
      P1[(T4)] = *(const f32x4*)(xsrc1 + (size_t)tc * 128);                    \
    }                                                                          \
    _Pragma("unroll")                                                          \
    for (int r = 0; r < 4; ++r) {                                              \
      float Ei = fexp2(ACUR[0][r]);   /* e^{-a_i} */                           \
      float Ef = fexp2(ACUR[1][r]);   /* e^{-a_f} */                           \
      float Eg = fexp2(ACUR[2][r]);   /* e^{+2a_g} */                          \
      float Eo = fexp2(ACUR[3][r]);   /* e^{-a_o} */                           \
      float u  = 1.0f + Ei;                                                    \
      float v  = Eg + 1.0f;                                                    \
      float w  = 1.0f + Ef;                                                    \
      float uv = u * v;                                                        \
      float num = __builtin_fmaf(c[r], uv, (Eg - 1.0f) * w);                   \
      float cc  = num * frcp(uv * w);                                          \
      c[r] = cc;                                                               \
      float E2 = fexp2(cc * (2.0f * L2E));                                     \
      hl[r] = (E2 - 1.0f) * frcp((E2 + 1.0f) * (1.0f + Eo));                   \
    }                                                                          \
    {                                                                          \
      unsigned w01 = cvt_pk(hl[0], hl[1]);                                     \
      unsigned w23 = cvt_pk(hl[2], hl[3]);                                     \
      *(short*)(hbW + hb_wr[0]) = (short)w01;                                  \
      *(short*)(hbW + hb_wr[1]) = (short)(w01 >> 16);                          \
      *(short*)(hbW + hb_wr[2]) = (short)w23;                                  \
      *(short*)(hbW + hb_wr[3]) = (short)(w23 >> 16);                          \
    }                                                                          \
    SYNC;                                                                      \
  }

    for (int t = 0; t < T_STEPS; t += 4) {
        WINDOW(t,     0, accA, accB);
        WINDOW(t + 1, 1, accB, accA);
        WINDOW(t + 2, 2, accA, accB);
        WINDOW(t + 3, 3, accB, accA);
    }
#undef WINDOW

    // ---------------- epilogue: out = h_last @ W_out.T + b_out -------------
#pragma unroll
    for (int r = 0; r < 4; ++r) {
        const int b = l4 * 4 + r;
        *(float*)(smem + HF_OFF + (b * 64 + jcol) * 4) = hl[r];
    }
    SYNC;

    if (tid < 160) {
        const int b = tid / 10;
        const int o = tid - b * 10;
        const f32x4* hf = (const f32x4*)(smem + HF_OFF + b * 256);
        const f32x4* wr = (const f32x4*)(W_out + o * 64);
        float s = b_out[o];
#pragma unroll
        for (int j4 = 0; j4 < 16; ++j4) {
            f32x4 h4 = hf[j4];
            f32x4 w4 = wr[j4];
            s += h4[0] * w4[0] + h4[1] * w4[1] + h4[2] * w4[2] + h4[3] * w4[3];
        }
        out[(b0 + b) * 10 + o] = s;
    }
}

extern "C" void kernel_launch(void* const* d_in, const int* in_sizes, int n_in,
                              void* d_out, int out_size, void* d_ws, size_t ws_size,
                              hipStream_t stream) {
    const float* x     = (const float*)d_in[0];
    const float* W_ih  = (const float*)d_in[1];
    const float* W_hh  = (const float*)d_in[2];
    const float* b_ih  = (const float*)d_in[3];
    const float* b_hh  = (const float*)d_in[4];
    const float* W_out = (const float*)d_in[5];
    const float* b_out = (const float*)d_in[6];
    (void)in_sizes; (void)n_in; (void)out_size; (void)d_ws; (void)ws_size;

    lstm_kernel<<<dim3(256), dim3(256), 0, stream>>>(
        x, W_ih, W_hh, b_ih, b_hh, W_out, b_out, (float*)d_out);
}

// Round 6
// 163.454 us; speedup vs baseline: 1.6292x; 1.0176x over previous
//
#include <hip/hip_runtime.h>

// Fused LSTM (B=4096, T=256, I=128, H=64) + projection (O=10).
// 256 WGs x 256 threads (4 waves, 1/SIMD); wave q owns interleaved gate slice
// {64*nt + 16*q + col} so i/f/g/o for one (b,j) share a lane.
// R6: 4-set rotating accumulators. Window t: h-MFMA finishes gates(t) in
// acc[t&3]; the 16 x-MFMAs build gx(t+2) in acc[(t+2)&3] and are issued
// BETWEEN the nonlin trans levels so exp2/rcp latency is hidden by MFMA +
// staging filler instead of sitting exposed at the window tail.
// log2e prescaled weights; shared-rcp gate algebra (7 trans per (b,j)).

typedef __attribute__((ext_vector_type(8))) short bf16x8;
typedef __attribute__((ext_vector_type(4))) float f32x4;
typedef __attribute__((ext_vector_type(2))) unsigned u32x2;

#define T_STEPS 256
#define L2E 1.44269504f

#define XF_OFF 0          // 4 x 4096B bf16 x-frag ring
#define H_OFF  16384      // 2 x 2048B bf16 h double buffer
#define HF_OFF 20480      // 4096B fp32 final h
#define LDS_SZ 24576

__device__ __forceinline__ short f2bf(float f) {           // prologue only
    unsigned u = __float_as_uint(f);
    u += 0x7FFFu + ((u >> 16) & 1u);
    return (short)(u >> 16);
}
__device__ __forceinline__ unsigned cvt_pk(float lo, float hi) {
    unsigned r;
    asm("v_cvt_pk_bf16_f32 %0, %1, %2" : "=v"(r) : "v"(lo), "v"(hi));
    return r;
}
__device__ __forceinline__ float frcp(float x) { float r; asm("v_rcp_f32 %0, %1" : "=v"(r) : "v"(x)); return r; }
__device__ __forceinline__ float fexp2(float x) { float r; asm("v_exp_f32 %0, %1" : "=v"(r) : "v"(x)); return r; }

#define MF(A, Bf, C) (C) = __builtin_amdgcn_mfma_f32_16x16x32_bf16((A), (Bf), (C), 0, 0, 0)
#define SYNC { asm volatile("s_waitcnt lgkmcnt(0)" ::: "memory"); __builtin_amdgcn_s_barrier(); }

__global__ __launch_bounds__(256, 1) void lstm_kernel(
    const float* __restrict__ x,
    const float* __restrict__ W_ih,
    const float* __restrict__ W_hh,
    const float* __restrict__ b_ih,
    const float* __restrict__ b_hh,
    const float* __restrict__ W_out,
    const float* __restrict__ b_out,
    float* __restrict__ out)
{
    __shared__ __align__(16) char smem[LDS_SZ];

    const int tid  = threadIdx.x;
    const int lane = tid & 63;
    const int q    = tid >> 6;
    const int l15  = lane & 15;
    const int l4   = lane >> 4;
    const int b0   = blockIdx.x * 16;

    // ---------------- weight fragments (exp2-prescaled) ----------------
    // nt 0(i),1(f),3(o): * -L2E  (sigmoid via exp2); nt 2(g): * +2*L2E (tanh)
    bf16x8 Bih[4][4];
    bf16x8 Bhh[4][2];
    f32x4  biasC[4];
#pragma unroll
    for (int nt = 0; nt < 4; ++nt) {
        const float scl = (nt == 2) ? (2.0f * L2E) : (-L2E);
        const int row = nt * 64 + q * 16 + l15;
#pragma unroll
        for (int ks = 0; ks < 4; ++ks) {
            const float* p = W_ih + row * 128 + ks * 32 + l4 * 8;
            f32x4 a = *(const f32x4*)p;
            f32x4 b = *(const f32x4*)(p + 4);
            bf16x8 wv;
#pragma unroll
            for (int j = 0; j < 4; ++j) { wv[j] = f2bf(a[j] * scl); wv[4 + j] = f2bf(b[j] * scl); }
            Bih[nt][ks] = wv;
        }
#pragma unroll
        for (int ks = 0; ks < 2; ++ks) {
            const float* p = W_hh + row * 64 + ks * 32 + l4 * 8;
            f32x4 a = *(const f32x4*)p;
            f32x4 b = *(const f32x4*)(p + 4);
            bf16x8 wv;
#pragma unroll
            for (int j = 0; j < 4; ++j) { wv[j] = f2bf(a[j] * scl); wv[4 + j] = f2bf(b[j] * scl); }
            Bhh[nt][ks] = wv;
        }
        const float bb = (b_ih[row] + b_hh[row]) * scl;
        biasC[nt] = (f32x4){bb, bb, bb, bb};
    }

    // ---------------- address maps ----------------
    int xf_rd[4];
#pragma unroll
    for (int ks = 0; ks < 4; ++ks)
        xf_rd[ks] = (((ks * 64 + lane) * 16) ^ ((ks & 3) << 6));

    const int jcol = q * 16 + l15;
    int hb_wr[4];
#pragma unroll
    for (int r = 0; r < 4; ++r) {
        const int b = l4 * 4 + r;
        hb_wr[r] = ((b * 128 + jcol * 2) ^ ((b & 7) << 4) ^ ((b >> 3) << 5));
    }
    int hb_rd[2];
#pragma unroll
    for (int ks = 0; ks < 2; ++ks)
        hb_rd[ks] = ((l15 * 128 + ks * 64 + l4 * 16) ^ ((l15 & 7) << 4) ^ ((l15 >> 3) << 5));

    // x staging: thread loads one f32x4 per step (32 threads cover a 512B row
    // contiguously; 2 passes cover 16 rows), writes 8B bf16 at the frag slot.
    const int srow = tid >> 5;
    const int scc  = tid & 31;
    const int sks  = scc >> 3;
    const int sl4  = (scc & 7) >> 1;
    const int sh   = scc & 1;
    const int xf_wr0 = (((sks * 64 + sl4 * 16 + srow) * 16 + sh * 8) ^ ((sks & 3) << 6));
    const int xf_wr1 = (((sks * 64 + sl4 * 16 + srow + 8) * 16 + sh * 8) ^ ((sks & 3) << 6));
    const float* xsrc0 = x + (size_t)(b0 + srow) * (T_STEPS * 128) + scc * 4;
    const float* xsrc1 = x + (size_t)(b0 + srow + 8) * (T_STEPS * 128) + scc * 4;

    // ---------------- prologue ----------------
#pragma unroll
    for (int s = 0; s < 3; ++s) {
        f32x4 v0 = *(const f32x4*)(xsrc0 + (size_t)s * 128);
        f32x4 v1 = *(const f32x4*)(xsrc1 + (size_t)s * 128);
        u32x2 wv0; wv0.x = cvt_pk(v0[0], v0[1]); wv0.y = cvt_pk(v0[2], v0[3]);
        u32x2 wv1; wv1.x = cvt_pk(v1[0], v1[1]); wv1.y = cvt_pk(v1[2], v1[3]);
        *(u32x2*)(smem + XF_OFF + s * 4096 + xf_wr0) = wv0;
        *(u32x2*)(smem + XF_OFF + s * 4096 + xf_wr1) = wv1;
    }
    f32x4 P0[4], P1[4];
#pragma unroll
    for (int s = 0; s < 4; ++s) {
        P0[s] = *(const f32x4*)(xsrc0 + (size_t)(s + 3) * 128);
        P1[s] = *(const f32x4*)(xsrc1 + (size_t)(s + 3) * 128);
    }
    ((unsigned long long*)(smem + H_OFF + 2048))[tid] = 0ull;  // h(-1)=0 (buf 1)

    SYNC;

    float c[4]  = {0.f, 0.f, 0.f, 0.f};
    float hl[4] = {0.f, 0.f, 0.f, 0.f};

    f32x4 acc[4][4];                      // [set = t&3][gate]

#define XGEMM(SET, SLOT)                                                       \
    {                                                                          \
        const char* xfb_ = smem + XF_OFF + (SLOT) * 4096;                      \
        bf16x8 Ax0 = *(const bf16x8*)(xfb_ + xf_rd[0]);                        \
        bf16x8 Ax1 = *(const bf16x8*)(xfb_ + xf_rd[1]);                        \
        bf16x8 Ax2 = *(const bf16x8*)(xfb_ + xf_rd[2]);                        \
        bf16x8 Ax3 = *(const bf16x8*)(xfb_ + xf_rd[3]);                        \
        acc[SET][0] = biasC[0]; acc[SET][1] = biasC[1];                        \
        acc[SET][2] = biasC[2]; acc[SET][3] = biasC[3];                        \
        MF(Ax0, Bih[0][0], acc[SET][0]); MF(Ax0, Bih[1][0], acc[SET][1]);      \
        MF(Ax0, Bih[2][0], acc[SET][2]); MF(Ax0, Bih[3][0], acc[SET][3]);      \
        MF(Ax1, Bih[0][1], acc[SET][0]); MF(Ax1, Bih[1][1], acc[SET][1]);      \
        MF(Ax1, Bih[2][1], acc[SET][2]); MF(Ax1, Bih[3][1], acc[SET][3]);      \
        MF(Ax2, Bih[0][2], acc[SET][0]); MF(Ax2, Bih[1][2], acc[SET][1]);      \
        MF(Ax2, Bih[2][2], acc[SET][2]); MF(Ax2, Bih[3][2], acc[SET][3]);      \
        MF(Ax3, Bih[0][3], acc[SET][0]); MF(Ax3, Bih[1][3], acc[SET][1]);      \
        MF(Ax3, Bih[2][3], acc[SET][2]); MF(Ax3, Bih[3][3], acc[SET][3]);      \
    }

    XGEMM(0, 0);                          // acc[0] = bias + gx(0)
    XGEMM(1, 1);                          // acc[1] = bias + gx(1)

    // Window tt (T4 = tt&3): h-MFMA -> gates(tt) in acc[T4]; E-level trans;
    // x-MFMAs gx(tt+2) -> acc[(T4+2)&3] (latency filler); algebra+rcp; stage
    // x(tt+3); E2; reload P; rcp2; h-write; barrier.
#define WINDOW(tt, T4)                                                         \
  {                                                                            \
    const char* hbR = smem + H_OFF + ((((T4) & 1) ^ 1) * 2048);                \
    char*       hbW = smem + H_OFF + (((T4) & 1) * 2048);                      \
    char*       xfw = smem + XF_OFF + ((((T4) + 3) & 3) * 4096);               \
    bf16x8 Ah0 = *(const bf16x8*)(hbR + hb_rd[0]);                             \
    bf16x8 Ah1 = *(const bf16x8*)(hbR + hb_rd[1]);                             \
    MF(Ah0, Bhh[0][0], acc[T4][0]); MF(Ah0, Bhh[1][0], acc[T4][1]);            \
    MF(Ah0, Bhh[2][0], acc[T4][2]); MF(Ah0, Bhh[3][0], acc[T4][3]);            \
    MF(Ah1, Bhh[0][1], acc[T4][0]); MF(Ah1, Bhh[1][1], acc[T4][1]);            \
    MF(Ah1, Bhh[2][1], acc[T4][2]); MF(Ah1, Bhh[3][1], acc[T4][3]);            \
    float Ei[4], Ef[4], Eg[4], Eo[4], E2[4];                                   \
    _Pragma("unroll")                                                          \
    for (int r = 0; r < 4; ++r) {                                              \
      Ei[r] = fexp2(acc[T4][0][r]);                                            \
      Ef[r] = fexp2(acc[T4][1][r]);                                            \
      Eg[r] = fexp2(acc[T4][2][r]);                                            \
      Eo[r] = fexp2(acc[T4][3][r]);                                            \
    }                                                                          \
    XGEMM((((T4) + 2) & 3), (((T4) + 2) & 3));                                 \
    _Pragma("unroll")                                                          \
    for (int r = 0; r < 4; ++r) {                                              \
      float u  = 1.0f + Ei[r];                                                 \
      float v  = Eg[r] + 1.0f;                                                 \
      float w  = 1.0f + Ef[r];                                                 \
      float uv = u * v;                                                        \
      float num = __builtin_fmaf(c[r], uv, (Eg[r] - 1.0f) * w);                \
      c[r] = num * frcp(uv * w);                                               \
    }                                                                          \
    {                                                                          \
      u32x2 wv0; wv0.x = cvt_pk(P0[(T4)][0], P0[(T4)][1]);                     \
      wv0.y = cvt_pk(P0[(T4)][2], P0[(T4)][3]);                                \
      u32x2 wv1; wv1.x = cvt_pk(P1[(T4)][0], P1[(T4)][1]);                     \
      wv1.y = cvt_pk(P1[(T4)][2], P1[(T4)][3]);                                \
      *(u32x2*)(xfw + xf_wr0) = wv0;                                           \
      *(u32x2*)(xfw + xf_wr1) = wv1;                                           \
    }                                                                          \
    _Pragma("unroll")                                                          \
    for (int r = 0; r < 4; ++r)                                                \
      E2[r] = fexp2(c[r] * (2.0f * L2E));                                      \
    {                                                                          \
      const int tc = ((tt) + 7) & 255;                                         \
      P0[(T4)] = *(const f32x4*)(xsrc0 + (size_t)tc * 128);                    \
      P1[(T4)] = *(const f32x4*)(xsrc1 + (size_t)tc * 128);                    \
    }                                                                          \
    _Pragma("unroll")                                                          \
    for (int r = 0; r < 4; ++r)                                                \
      hl[r] = (E2[r] - 1.0f) * frcp((E2[r] + 1.0f) * (1.0f + Eo[r]));          \
    {                                                                          \
      unsigned w01 = cvt_pk(hl[0], hl[1]);                                     \
      unsigned w23 = cvt_pk(hl[2], hl[3]);                                     \
      *(short*)(hbW + hb_wr[0]) = (short)w01;                                  \
      *(short*)(hbW + hb_wr[1]) = (short)(w01 >> 16);                          \
      *(short*)(hbW + hb_wr[2]) = (short)w23;                                  \
      *(short*)(hbW + hb_wr[3]) = (short)(w23 >> 16);                          \
    }                                                                          \
    SYNC;                                                                      \
  }

    for (int t = 0; t < T_STEPS; t += 4) {
        WINDOW(t,     0);
        WINDOW(t + 1, 1);
        WINDOW(t + 2, 2);
        WINDOW(t + 3, 3);
    }
#undef WINDOW
#undef XGEMM

    // ---------------- epilogue: out = h_last @ W_out.T + b_out -------------
#pragma unroll
    for (int r = 0; r < 4; ++r) {
        const int b = l4 * 4 + r;
        *(float*)(smem + HF_OFF + (b * 64 + jcol) * 4) = hl[r];
    }
    SYNC;

    if (tid < 160) {
        const int b = tid / 10;
        const int o = tid - b * 10;
        const f32x4* hf = (const f32x4*)(smem + HF_OFF + b * 256);
        const f32x4* wr = (const f32x4*)(W_out + o * 64);
        float s = b_out[o];
#pragma unroll
        for (int j4 = 0; j4 < 16; ++j4) {
            f32x4 h4 = hf[j4];
            f32x4 w4 = wr[j4];
            s += h4[0] * w4[0] + h4[1] * w4[1] + h4[2] * w4[2] + h4[3] * w4[3];
        }
        out[(b0 + b) * 10 + o] = s;
    }
}

extern "C" void kernel_launch(void* const* d_in, const int* in_sizes, int n_in,
                              void* d_out, int out_size, void* d_ws, size_t ws_size,
                              hipStream_t stream) {
    const float* x     = (const float*)d_in[0];
    const float* W_ih  = (const float*)d_in[1];
    const float* W_hh  = (const float*)d_in[2];
    const float* b_ih  = (const float*)d_in[3];
    const float* b_hh  = (const float*)d_in[4];
    const float* W_out = (const float*)d_in[5];
    const float* b_out = (const float*)d_in[6];
    (void)in_sizes; (void)n_in; (void)out_size; (void)d_ws; (void)ws_size;

    lstm_kernel<<<dim3(256), dim3(256), 0, stream>>>(
        x, W_ih, W_hh, b_ih, b_hh, W_out, b_out, (float*)d_out);
}